// Round 1
// 942.344 us; speedup vs baseline: 1.0126x; 1.0126x over previous
//
#include <hip/hip_runtime.h>
#include <math.h>

// Problem constants (reference file)
#define NROWS 131072
#define NCOLS 1000
#define NV4   250                 // float4 chunks per row (1000/4)
#define TAU_F       6.9077552789821368f   // log(1000)
#define INV_E_F     0.36787944117144233f
#define E_F         2.7182818284590452f
#define INV_BATCH_F (1.0f / 131072.0f)

__device__ __forceinline__ float wave_max(float v) {
#pragma unroll
    for (int off = 32; off >= 1; off >>= 1)
        v = fmaxf(v, __shfl_xor(v, off, 64));
    return v;
}

__device__ __forceinline__ float wave_sum(float v) {
#pragma unroll
    for (int off = 32; off >= 1; off >>= 1)
        v += __shfl_xor(v, off, 64);
    return v;
}

// Kernel 1 (bulk, BW-bound): one wave per row, 4 rows per 256-thread block.
// Streams the row, reduces (max, expsum, t·x, Σt, Σ|x−t|) and stores only
// (sa, l_i) per row. All Lambert-W / sigma work is deferred to kernel 2.
__global__ __launch_bounds__(256) void superloss_row_kernel(
        const float* __restrict__ logits,
        const float* __restrict__ targets,
        float2* __restrict__ rowdat)
{
    const int wave = threadIdx.x >> 6;
    const int lane = threadIdx.x & 63;
    const int row  = blockIdx.x * 4 + wave;

    const float4* lg = (const float4*)(logits  + (size_t)row * NCOLS);
    const float4* tg = (const float4*)(targets + (size_t)row * NCOLS);

    // Register-stage the whole row: lane handles float4 indices lane+64k, k<4.
    float4 x[4], t[4];
#pragma unroll
    for (int k = 0; k < 4; ++k) {
        const int j = lane + 64 * k;
        if (j < NV4) { x[k] = lg[j]; t[k] = tg[j]; }
        else {
            x[k] = make_float4(-INFINITY, -INFINITY, -INFINITY, -INFINITY);
            t[k] = make_float4(0.f, 0.f, 0.f, 0.f);
        }
    }

    // Pass 1: row max
    float m = -INFINITY;
#pragma unroll
    for (int k = 0; k < 4; ++k) {
        m = fmaxf(m, fmaxf(fmaxf(x[k].x, x[k].y), fmaxf(x[k].z, x[k].w)));
    }
    m = wave_max(m);

    // Pass 2 (registers): expsum, t·x, Σt, Σ|x−t|
    float se = 0.f, tx = 0.f, ts = 0.f, sa = 0.f;
#pragma unroll
    for (int k = 0; k < 4; ++k) {
        const int j = lane + 64 * k;
        if (j < NV4) {
            se += __expf(x[k].x - m) + __expf(x[k].y - m)
                + __expf(x[k].z - m) + __expf(x[k].w - m);
            tx += t[k].x * x[k].x + t[k].y * x[k].y
                + t[k].z * x[k].z + t[k].w * x[k].w;
            ts += t[k].x + t[k].y + t[k].z + t[k].w;
            sa += fabsf(x[k].x - t[k].x) + fabsf(x[k].y - t[k].y)
                + fabsf(x[k].z - t[k].z) + fabsf(x[k].w - t[k].w);
        }
    }
#pragma unroll
    for (int off = 32; off >= 1; off >>= 1) {
        se += __shfl_xor(se, off, 64);
        tx += __shfl_xor(tx, off, 64);
        ts += __shfl_xor(ts, off, 64);
        sa += __shfl_xor(sa, off, 64);
    }

    if (lane == 0) {
        const float lse = m + __logf(se);
        const float l_i = lse * ts - tx;               // -Σ t*(x - lse)
        rowdat[row] = make_float2(sa, l_i);
    }
}

// Per-row scalar tail: Lambert W0 via Halley, identical op sequence to the
// previous in-wave version, so contrib is bitwise-identical per row.
__device__ __forceinline__ float row_contrib(const float2 d) {
    const float sa  = d.x;
    const float l_i = d.y;
    const float y   = 0.5f * fmaxf(-2.0f * INV_E_F, l_i - TAU_F);  // LAM=1

    float p = sqrtf(fmaxf(2.0f * (E_F * y + 1.0f), 0.0f));
    float w = (y < -0.25f) ? (p - 1.0f) : log1pf(fmaxf(y, -0.25f));
#pragma unroll
    for (int it = 0; it < 12; ++it) {
        const float ew    = __expf(w);
        const float f     = w * ew - y;
        float denom = ew * (w + 1.0f) - (w + 2.0f) * f / (2.0f * w + 2.0f + 1e-12f);
        denom = (fabsf(denom) < 1e-12f) ? 1e-12f : denom;
        const float step  = f / denom;
        w = (fabsf(f) < 1e-12f) ? w : (w - step);
    }

    const float sigma = __expf(-w);                    // log(sigma) = -w
    return (sa - TAU_F * (float)NCOLS) * sigma + (float)NCOLS * (w * w);
}

// Kernel 2 (tail + stage-1 reduce): 256 blocks × 256 threads; each thread
// finishes TWO rows (base+t, base+256+t) and the block sums 512 contiguous
// rows — exactly the old reduce1 topology, so the sum is bitwise-identical.
__global__ __launch_bounds__(256) void superloss_tail_reduce(
        const float2* __restrict__ rowdat, float* __restrict__ out)
{
    const int base = blockIdx.x * 512;
    float s = row_contrib(rowdat[base + threadIdx.x])
            + row_contrib(rowdat[base + 256 + threadIdx.x]);
    s = wave_sum(s);
    __shared__ float ls[4];
    if ((threadIdx.x & 63) == 0) ls[threadIdx.x >> 6] = s;
    __syncthreads();
    if (threadIdx.x == 0) out[blockIdx.x] = ls[0] + ls[1] + ls[2] + ls[3];
}

// Kernel 3: single block sums the 256 block partials and scales.
__global__ __launch_bounds__(256) void superloss_reduce2(
        const float* __restrict__ part, float* __restrict__ out)
{
    float s = part[threadIdx.x];
    s = wave_sum(s);
    __shared__ float ls[4];
    if ((threadIdx.x & 63) == 0) ls[threadIdx.x >> 6] = s;
    __syncthreads();
    if (threadIdx.x == 0) out[0] = (ls[0] + ls[1] + ls[2] + ls[3]) * INV_BATCH_F;
}

extern "C" void kernel_launch(void* const* d_in, const int* in_sizes, int n_in,
                              void* d_out, int out_size, void* d_ws, size_t ws_size,
                              hipStream_t stream) {
    const float* logits  = (const float*)d_in[0];
    const float* targets = (const float*)d_in[1];
    float* out   = (float*)d_out;
    float2* rowdat = (float2*)d_ws;               // NROWS float2 (1 MB)
    float* part2   = (float*)(rowdat + NROWS);    // 256 floats

    superloss_row_kernel<<<NROWS / 4, 256, 0, stream>>>(logits, targets, rowdat);
    superloss_tail_reduce<<<256, 256, 0, stream>>>(rowdat, part2);
    superloss_reduce2<<<1, 256, 0, stream>>>(part2, out);
}